// Round 6
// baseline (39.144 us; speedup 1.0000x reference)
//
#include <hip/hip_runtime.h>
#include <hip/hip_bf16.h>

#define B_    32
#define C_    256
#define NT    512     // T_TEXT
#define TFEAT 2048    // T_FEAT
#define TT    32      // frames per tile
#define UW    96      // union token window per tile (3 MFMA K-steps)
#define PRE   32
#define DELTA 0.1f
#define PSTR  104     // Pt LDS row stride in bf16 elems (52 dwords)
#define XSTR  520     // xs LDS row stride (bf16 elems)
#define OSTR  516     // outbuf LDS row stride (f32)

// ws layout: P̂ [32][64][32][96] bf16 (12.58 MB) then lotab [32][64] int (8 KB)
#define PHAT_ELEMS ((size_t)B_ * 64 * TT * UW)
#define WS_NEED (PHAT_ELEMS * 2 + (size_t)B_ * 64 * 4)

typedef __attribute__((ext_vector_type(4))) float f32x4;
typedef __attribute__((ext_vector_type(8))) unsigned short u16x8;
typedef __attribute__((ext_vector_type(8))) __bf16 bf16x8;

static __device__ inline unsigned short f2bfbits(float f) {
    __bf16 h = (__bf16)f;
    return __builtin_bit_cast(unsigned short, h);
}
static __device__ inline float bf2f(unsigned short h) {
    return __uint_as_float(((unsigned)h) << 16);
}

// ---- Kernel P: scan + window softmax -> normalized bf16 P̂ (linear) + lotab --
__global__ __launch_bounds__(256, 2) void p_kernel(const float* __restrict__ w,
                                                   unsigned short* __restrict__ phat,
                                                   int* __restrict__ lotab) {
    __shared__ float cs[NT];
    __shared__ float wsum[8];
    __shared__ unsigned short Pt[TT][PSTR];
    __shared__ int sLO[4];

    int tid  = threadIdx.x;
    int bx   = blockIdx.x;
    int b    = bx & 31;          // same-b blocks -> same XCD L2
    int tg   = bx >> 5;          // 4 tiles: tg*4 .. tg*4+3
    int lane = tid & 63;
    int wv   = tid >> 6;

    // scan: centers
    float v0 = w[b * NT + tid];
    float v1 = w[b * NT + 256 + tid];
    float s0 = v0, s1 = v1;
#pragma unroll
    for (int off = 1; off < 64; off <<= 1) {
        float t0 = __shfl_up(s0, off);
        float t1 = __shfl_up(s1, off);
        if (lane >= off) { s0 += t0; s1 += t1; }
    }
    if (lane == 63) { wsum[wv] = s0; wsum[4 + wv] = s1; }
    __syncthreads();
    float pre0 = 0.f;
    float pre1 = wsum[0] + wsum[1] + wsum[2] + wsum[3];
#pragma unroll
    for (int i = 0; i < 4; ++i) if (i < wv) pre0 += wsum[i];
#pragma unroll
    for (int i = 0; i < 4; ++i) if (i < wv) pre1 += wsum[4 + i];
    cs[tid]       = pre0 + s0 - 0.5f * v0;
    cs[256 + tid] = pre1 + s1 - 0.5f * v1;
    __syncthreads();

    // ballot window search: 4 tiles in parallel on wave 0
    if (wv == 0) {
        int gid = lane >> 4;
        int k   = lane & 15;
        float ft = (float)((tg * 4 + gid) * TT);
        bool p = cs[32 * k + 31] < ft;
        unsigned long long m = __ballot(p);
        int K = __popcll((m >> (gid * 16)) & 0xFFFFull);
        int n;
        if (K >= 16) {
            n = NT;
        } else {
            int base = 32 * K;
            bool pa = cs[base + k] < ft;
            bool pb = cs[base + 16 + k] < ft;
            unsigned long long ma = __ballot(pa);
            unsigned long long mb = __ballot(pb);
            n = base + __popcll((ma >> (gid * 16)) & 0xFFFFull)
                     + __popcll((mb >> (gid * 16)) & 0xFFFFull);
        }
        if (k == 0) {
            int n1 = n < NT - 1 ? n : NT - 1;
            int n0 = n - 1 > 0 ? n - 1 : 0;
            int nstar = (fabsf(ft - cs[n0]) <= fabsf(ft - cs[n1])) ? n0 : n1;
            int L = (nstar - PRE) & ~3;
            if (L < 0) L = 0;
            if (L > NT - UW) L = NT - UW;
            sLO[gid] = L;
            lotab[b * 64 + tg * 4 + gid] = L;
        }
    }
    __syncthreads();

    int g = tid >> 3, j = tid & 7;

    for (int it = 0; it < 4; ++it) {
        int tile = tg * 4 + it;
        int LO = sLO[it];
        float ft = (float)(tile * TT + g);
        float e[12];
        float mx = -1e30f;
#pragma unroll
        for (int k = 0; k < 12; ++k) {
            float d = ft - cs[LO + j + 8 * k];
            e[k] = -DELTA * d * d;
            mx = fmaxf(mx, e[k]);
        }
        mx = fmaxf(mx, __shfl_xor(mx, 1));
        mx = fmaxf(mx, __shfl_xor(mx, 2));
        mx = fmaxf(mx, __shfl_xor(mx, 4));
        float p[12];
        float sum = 0.f;
#pragma unroll
        for (int k = 0; k < 12; ++k) {
            p[k] = __expf(e[k] - mx);
            sum += p[k];
        }
        sum += __shfl_xor(sum, 1);
        sum += __shfl_xor(sum, 2);
        sum += __shfl_xor(sum, 4);
        float inv = 1.f / fmaxf(sum, 1e-30f);
#pragma unroll
        for (int k = 0; k < 12; ++k)
            Pt[g][j + 8 * k] = f2bfbits(p[k] * inv);
        __syncthreads();

        // linear dump: 6144 B/tile, thread -> 6 consecutive dwords
        const unsigned* pw = (const unsigned*)&Pt[0][0];
        unsigned* gd = (unsigned*)phat + (size_t)(b * 64 + tile) * 1536 + tid * 6;
        int a = tid >> 3, r6 = tid & 7;
#pragma unroll
        for (int q = 0; q < 6; ++q)
            gd[q] = pw[a * (PSTR / 2) + r6 * 6 + q];
        __syncthreads();
    }
}

// ---- Kernel G: per (b, 16-ch group), x in LDS, MFMA, linear 2KB dumps -------
__global__ __launch_bounds__(256, 2) void g_kernel(const float* __restrict__ x,
                                                   const unsigned short* __restrict__ phat,
                                                   const int* __restrict__ lotab,
                                                   float* __restrict__ out) {
    __shared__ unsigned short xs[16][XSTR];   // 16.6 KB bf16 x rows
    __shared__ float outbuf[16][OSTR];        // 33 KB f32 out accumulation

    int tid  = threadIdx.x;
    int bx   = blockIdx.x;
    int b    = bx & 31;          // same-b blocks -> same XCD L2
    int cg   = bx >> 5;
    int c0   = cg * 16;
    int lane = tid & 63;
    int w    = tid >> 6;

    // stage x[b][c0..c0+15][0:512] -> LDS bf16
    {
        int c = tid >> 4, k = tid & 15;
        const float* xr = x + ((size_t)(b * C_ + c0 + c)) * NT + k * 32;
#pragma unroll
        for (int jj = 0; jj < 4; ++jj) {
            f32x4 a0 = *reinterpret_cast<const f32x4*>(xr + jj * 8);
            f32x4 a1 = *reinterpret_cast<const f32x4*>(xr + jj * 8 + 4);
            bf16x8 vv;
#pragma unroll
            for (int q = 0; q < 4; ++q) {
                vv[q]     = (__bf16)a0[q];
                vv[q + 4] = (__bf16)a1[q];
            }
            *reinterpret_cast<bf16x8*>(&xs[c][k * 32 + jj * 8]) = vv;
        }
    }
    __syncthreads();

    int cc = lane & 15;     // channel within group / D column
    int kg = lane >> 4;     // k-group / D row quad

    for (int s = 0; s < 16; ++s) {
        int tile = s * 4 + w;            // each wave owns one 32-frame tile
        int LO = lotab[b * 64 + tile];

        // A fragments: P̂ from global (L2-resident, linear layout)
        const unsigned short* ap = phat + (size_t)(b * 64 + tile) * (TT * UW);
        bf16x8 af[2][3];
#pragma unroll
        for (int mt = 0; mt < 2; ++mt)
#pragma unroll
            for (int ks = 0; ks < 3; ++ks)
                af[mt][ks] = __builtin_bit_cast(bf16x8,
                    *reinterpret_cast<const u16x8*>(
                        ap + (mt * 16 + cc) * UW + ks * 32 + kg * 8));

        // B fragments: x^T from LDS
        bf16x8 bfg[3];
#pragma unroll
        for (int ks = 0; ks < 3; ++ks)
            bfg[ks] = __builtin_bit_cast(bf16x8,
                *reinterpret_cast<const u16x8*>(&xs[cc][LO + ks * 32 + kg * 8]));

        f32x4 acc[2];
        acc[0] = (f32x4){0.f, 0.f, 0.f, 0.f};
        acc[1] = (f32x4){0.f, 0.f, 0.f, 0.f};
#pragma unroll
        for (int mt = 0; mt < 2; ++mt)
#pragma unroll
            for (int ks = 0; ks < 3; ++ks)
                acc[mt] = __builtin_amdgcn_mfma_f32_16x16x32_bf16(
                    af[mt][ks], bfg[ks], acc[mt], 0, 0, 0);

        // accumulate into LDS outbuf: lane holds channel cc, 4 consecutive frames
        int toff = (s & 3) * 128 + w * 32 + kg * 4;
#pragma unroll
        for (int mt = 0; mt < 2; ++mt)
            *reinterpret_cast<f32x4*>(&outbuf[cc][toff + mt * 16]) = acc[mt];

        if ((s & 3) == 3) {
            __syncthreads();
            // dump 16 rows x 2KB contiguous (nt dwordx4 streams)
            int row = tid >> 4, kk = tid & 15;
            int tb = (s >> 2) * 512;
            float* ob = out + ((size_t)(b * C_ + c0 + row)) * TFEAT + tb;
#pragma unroll
            for (int jj = 0; jj < 8; ++jj) {
                f32x4 v = *reinterpret_cast<const f32x4*>(&outbuf[row][(kk + 16 * jj) * 4]);
                __builtin_nontemporal_store(v,
                    reinterpret_cast<f32x4*>(ob + (kk + 16 * jj) * 4));
            }
            __syncthreads();
        }
    }
}

// ---- fallback (round-5 fused kernel) if ws too small ------------------------
#define TPB   2
#define NGRP  32
#define TSTR  36

__global__ __launch_bounds__(256, 2) void fused_fallback(const float* __restrict__ x,
                                                         const float* __restrict__ w,
                                                         float* __restrict__ out) {
    __shared__ float cs[NT];
    __shared__ float wsum[8];
    __shared__ unsigned short Pt[TT][PSTR];
    __shared__ float Sinv[TT];
    __shared__ int sLO[TPB];
    __shared__ float trans[4][16][TSTR];

    int tid  = threadIdx.x;
    int bx   = blockIdx.x;
    int b    = bx & 31;
    int grp  = bx >> 5;
    int lane = tid & 63;
    int wv   = tid >> 6;

    float v0 = w[b * NT + tid];
    float v1 = w[b * NT + 256 + tid];
    float s0 = v0, s1 = v1;
#pragma unroll
    for (int off = 1; off < 64; off <<= 1) {
        float t0 = __shfl_up(s0, off);
        float t1 = __shfl_up(s1, off);
        if (lane >= off) { s0 += t0; s1 += t1; }
    }
    if (lane == 63) { wsum[wv] = s0; wsum[4 + wv] = s1; }
    __syncthreads();
    float pre0 = 0.f;
    float pre1 = wsum[0] + wsum[1] + wsum[2] + wsum[3];
#pragma unroll
    for (int i = 0; i < 4; ++i) if (i < wv) pre0 += wsum[i];
#pragma unroll
    for (int i = 0; i < 4; ++i) if (i < wv) pre1 += wsum[4 + i];
    cs[tid]       = pre0 + s0 - 0.5f * v0;
    cs[256 + tid] = pre1 + s1 - 0.5f * v1;
    __syncthreads();

    if (wv == 0) {
        int gid = lane >> 4;
        int k   = lane & 15;
        if (gid < TPB) {
            float ft = (float)((grp * TPB + gid) * TT);
            bool p = cs[32 * k + 31] < ft;
            unsigned long long m = __ballot(p);
            int K = __popcll((m >> (gid * 16)) & 0xFFFFull);
            int n;
            if (K >= 16) {
                n = NT;
            } else {
                int base = 32 * K;
                bool pa = cs[base + k] < ft;
                bool pb = cs[base + 16 + k] < ft;
                unsigned long long ma = __ballot(pa);
                unsigned long long mb = __ballot(pb);
                n = base + __popcll((ma >> (gid * 16)) & 0xFFFFull)
                         + __popcll((mb >> (gid * 16)) & 0xFFFFull);
            }
            if (k == 0) {
                int n1 = n < NT - 1 ? n : NT - 1;
                int n0 = n - 1 > 0 ? n - 1 : 0;
                int nstar = (fabsf(ft - cs[n0]) <= fabsf(ft - cs[n1])) ? n0 : n1;
                int L = (nstar - PRE) & ~3;
                if (L < 0) L = 0;
                if (L > NT - UW) L = NT - UW;
                sLO[gid] = L;
            }
        }
    }
    __syncthreads();

    int g = tid >> 3, j = tid & 7;
    int arow = lane & 15, kg = lane >> 4;
    int rr = lane >> 3, tq = lane & 7;

    for (int it = 0; it < TPB; ++it) {
        {
            int LO = sLO[it];
            float ft = (float)((grp * TPB + it) * TT + g);
            float e[12];
            float mx = -1e30f;
#pragma unroll
            for (int k = 0; k < 12; ++k) {
                float d = ft - cs[LO + j + 8 * k];
                e[k] = -DELTA * d * d;
                mx = fmaxf(mx, e[k]);
            }
            mx = fmaxf(mx, __shfl_xor(mx, 1));
            mx = fmaxf(mx, __shfl_xor(mx, 2));
            mx = fmaxf(mx, __shfl_xor(mx, 4));
            float sum = 0.f;
#pragma unroll
            for (int k = 0; k < 12; ++k) {
                unsigned short pbv = f2bfbits(__expf(e[k] - mx));
                sum += bf2f(pbv);
                Pt[g][j + 8 * k] = pbv;
            }
            sum += __shfl_xor(sum, 1);
            sum += __shfl_xor(sum, 2);
            sum += __shfl_xor(sum, 4);
            if (j == 0) Sinv[g] = 1.f / fmaxf(sum, 1e-30f);
        }
        __syncthreads();

        int LO = sLO[it];
        bf16x8 pfrag[2][3];
#pragma unroll
        for (int tt = 0; tt < 2; ++tt)
#pragma unroll
            for (int ks = 0; ks < 3; ++ks)
                pfrag[tt][ks] = __builtin_bit_cast(bf16x8,
                    *reinterpret_cast<const u16x8*>(
                        &Pt[tt * 16 + arow][ks * 32 + kg * 8]));

        f32x4 acc[2][4];
#pragma unroll
        for (int tt = 0; tt < 2; ++tt)
#pragma unroll
            for (int m = 0; m < 4; ++m)
                acc[tt][m] = (f32x4){0.f, 0.f, 0.f, 0.f};

        const float* xb = x + ((size_t)b * C_) * NT + LO + kg * 8;
#pragma unroll
        for (int m = 0; m < 4; ++m) {
            const float* xr = xb + (size_t)(wv * 64 + m * 16 + arow) * NT;
            bf16x8 xf[3];
#pragma unroll
            for (int ks = 0; ks < 3; ++ks) {
                f32x4 a0 = *reinterpret_cast<const f32x4*>(xr + ks * 32);
                f32x4 a1 = *reinterpret_cast<const f32x4*>(xr + ks * 32 + 4);
                bf16x8 vv;
#pragma unroll
                for (int q = 0; q < 4; ++q) {
                    vv[q]     = (__bf16)a0[q];
                    vv[q + 4] = (__bf16)a1[q];
                }
                xf[ks] = vv;
            }
#pragma unroll
            for (int tt = 0; tt < 2; ++tt)
#pragma unroll
                for (int ks = 0; ks < 3; ++ks)
                    acc[tt][m] = __builtin_amdgcn_mfma_f32_16x16x32_bf16(
                        pfrag[tt][ks], xf[ks], acc[tt][m], 0, 0, 0);
        }

        int t0f = (grp * TPB + it) * TT;
        float* ob = out + ((size_t)b * C_) * TFEAT + t0f;
        f32x4 sv0 = *reinterpret_cast<const f32x4*>(&Sinv[kg * 4]);
        f32x4 sv1 = *reinterpret_cast<const f32x4*>(&Sinv[16 + kg * 4]);
#pragma unroll
        for (int m = 0; m < 4; ++m) {
            *reinterpret_cast<f32x4*>(&trans[wv][arow][kg * 4])      = acc[0][m] * sv0;
            *reinterpret_cast<f32x4*>(&trans[wv][arow][16 + kg * 4]) = acc[1][m] * sv1;
            f32x4 o0 = *reinterpret_cast<const f32x4*>(&trans[wv][rr][tq * 4]);
            f32x4 o1 = *reinterpret_cast<const f32x4*>(&trans[wv][8 + rr][tq * 4]);
            int cq = wv * 64 + m * 16;
            *reinterpret_cast<f32x4*>(ob + (size_t)(cq + rr) * TFEAT + tq * 4)     = o0;
            *reinterpret_cast<f32x4*>(ob + (size_t)(cq + 8 + rr) * TFEAT + tq * 4) = o1;
        }
        __syncthreads();
    }
}

extern "C" void kernel_launch(void* const* d_in, const int* in_sizes, int n_in,
                              void* d_out, int out_size, void* d_ws, size_t ws_size,
                              hipStream_t stream) {
    const float* x = (const float*)d_in[0];
    const float* w = (const float*)d_in[1];
    // x_mask / y_mask are all-True: ignored.
    float* out = (float*)d_out;

    if (ws_size >= WS_NEED) {
        unsigned short* phat = (unsigned short*)d_ws;
        int* lotab = (int*)((char*)d_ws + PHAT_ELEMS * 2);
        hipLaunchKernelGGL(p_kernel, dim3(B_ * 16), dim3(256), 0, stream, w, phat, lotab);
        hipLaunchKernelGGL(g_kernel, dim3(B_ * 16), dim3(256), 0, stream,
                           x, phat, lotab, out);
    } else {
        hipLaunchKernelGGL(fused_fallback, dim3(B_ * NGRP), dim3(256), 0, stream,
                           x, w, out);
    }
}

// Round 7
// 36.383 us; speedup vs baseline: 1.0759x; 1.0759x over previous
//
#include <hip/hip_runtime.h>
#include <hip/hip_bf16.h>

#define B_    32
#define C_    256
#define NT    512     // T_TEXT
#define TFEAT 2048    // T_FEAT
#define TT    32      // frames per tile
#define UW    96      // union token window per tile (3 MFMA K-steps)
#define PRE   32
#define DELTA 0.1f

typedef __attribute__((ext_vector_type(4))) float f32x4;
typedef __attribute__((ext_vector_type(8))) unsigned short u16x8;
typedef __attribute__((ext_vector_type(8))) __bf16 bf16x8;

static __device__ inline unsigned short f2bfbits(float f) {
    __bf16 h = (__bf16)f;                       // hardware RNE cvt
    return __builtin_bit_cast(unsigned short, h);
}
static __device__ inline float bf2f(unsigned short h) {
    return __uint_as_float(((unsigned)h) << 16);
}

// ---- Kernel 1: scan -> centers (global) + per-tile window starts ------------
__global__ __launch_bounds__(256) void prep_kernel(const float* __restrict__ w,
                                                   float* __restrict__ cout,
                                                   int* __restrict__ lotab) {
    __shared__ float cs[NT];
    __shared__ float wsum[8];
    int tid  = threadIdx.x;
    int b    = blockIdx.x;
    int lane = tid & 63;
    int wv   = tid >> 6;

    float v0 = w[b * NT + tid];
    float v1 = w[b * NT + 256 + tid];
    float s0 = v0, s1 = v1;
#pragma unroll
    for (int off = 1; off < 64; off <<= 1) {
        float t0 = __shfl_up(s0, off);
        float t1 = __shfl_up(s1, off);
        if (lane >= off) { s0 += t0; s1 += t1; }
    }
    if (lane == 63) { wsum[wv] = s0; wsum[4 + wv] = s1; }
    __syncthreads();
    float pre0 = 0.f;
    float pre1 = wsum[0] + wsum[1] + wsum[2] + wsum[3];
#pragma unroll
    for (int i = 0; i < 4; ++i) if (i < wv) pre0 += wsum[i];
#pragma unroll
    for (int i = 0; i < 4; ++i) if (i < wv) pre1 += wsum[4 + i];
    float c0 = pre0 + s0 - 0.5f * v0;
    float c1 = pre1 + s1 - 0.5f * v1;
    cs[tid]       = c0;
    cs[256 + tid] = c1;
    cout[b * NT + tid]       = c0;
    cout[b * NT + 256 + tid] = c1;
    __syncthreads();

    // 64 parallel binary searches -> per-tile union-window start
    if (tid < TFEAT / TT) {
        float ft = (float)(tid * TT);
        int lo = 0, hi = NT;
        while (hi > lo) {
            int mid = (lo + hi) >> 1;
            if (cs[mid] < ft) lo = mid + 1; else hi = mid;
        }
        int n1 = lo < NT - 1 ? lo : NT - 1;
        int n0 = lo - 1 > 0 ? lo - 1 : 0;
        int nstar = (fabsf(ft - cs[n0]) <= fabsf(ft - cs[n1])) ? n0 : n1;
        int L = (nstar - PRE) & ~3;
        if (L < 0) L = 0;
        if (L > NT - UW) L = NT - UW;
        lotab[b * (TFEAT / TT) + tid] = L;
    }
}

// ---- Kernel 2: one wave = one (b, 32-frame tile); no LDS, no barriers -------
__global__ __launch_bounds__(64) void g_kernel(const float* __restrict__ x,
                                               const float* __restrict__ cw,
                                               const int* __restrict__ lotab,
                                               float* __restrict__ out) {
    int bx   = blockIdx.x;
    int b    = bx & 31;          // same-b blocks share wgid%8 -> same XCD L2
    int tile = bx >> 5;
    int l    = threadIdx.x;      // 0..63
    int fr   = l & 15;           // frame-within-16 (A row) / channel col (D)
    int kg   = l >> 4;           // k-group
    int LO   = lotab[b * (TFEAT / TT) + tile];   // uniform -> s_load
    int t0   = tile * TT;

    // ---- centers for this lane's 24 k-slots ----
    const float* cp = cw + b * NT + LO + kg * 8;
    f32x4 cv[6];
#pragma unroll
    for (int ks = 0; ks < 3; ++ks) {
        cv[2 * ks]     = *reinterpret_cast<const f32x4*>(cp + ks * 32);
        cv[2 * ks + 1] = *reinterpret_cast<const f32x4*>(cp + ks * 32 + 4);
    }

    // ---- in-register softmax for frames fr (tt=0) and 16+fr (tt=1) ----
    float ft0 = (float)(t0 + fr);
    float ft1 = (float)(t0 + 16 + fr);
    float e0[24], e1[24];
    float mx0 = -1e30f, mx1 = -1e30f;
#pragma unroll
    for (int ks = 0; ks < 3; ++ks)
#pragma unroll
        for (int q = 0; q < 8; ++q) {
            float c = cv[2 * ks + (q >> 2)][q & 3];
            float d0 = ft0 - c, d1 = ft1 - c;
            float a0 = -DELTA * d0 * d0;
            float a1 = -DELTA * d1 * d1;
            e0[ks * 8 + q] = a0; mx0 = fmaxf(mx0, a0);
            e1[ks * 8 + q] = a1; mx1 = fmaxf(mx1, a1);
        }
    mx0 = fmaxf(mx0, __shfl_xor(mx0, 16)); mx0 = fmaxf(mx0, __shfl_xor(mx0, 32));
    mx1 = fmaxf(mx1, __shfl_xor(mx1, 16)); mx1 = fmaxf(mx1, __shfl_xor(mx1, 32));

    bf16x8 af0[3], af1[3];
    float sum0 = 0.f, sum1 = 0.f;
#pragma unroll
    for (int ks = 0; ks < 3; ++ks)
#pragma unroll
        for (int q = 0; q < 8; ++q) {
            unsigned short p0 = f2bfbits(__expf(e0[ks * 8 + q] - mx0));
            unsigned short p1 = f2bfbits(__expf(e1[ks * 8 + q] - mx1));
            sum0 += bf2f(p0);            // sum of bf16-rounded values
            sum1 += bf2f(p1);
            af0[ks][q] = __builtin_bit_cast(__bf16, p0);
            af1[ks][q] = __builtin_bit_cast(__bf16, p1);
        }
    sum0 += __shfl_xor(sum0, 16); sum0 += __shfl_xor(sum0, 32);
    sum1 += __shfl_xor(sum1, 16); sum1 += __shfl_xor(sum1, 32);
    float inv0 = 1.f / fmaxf(sum0, 1e-30f);
    float inv1 = 1.f / fmaxf(sum1, 1e-30f);

    // redistribute Sinv to D-row owners: lane needs frames kg*4+r (and +16)
    f32x4 sv0, sv1;
#pragma unroll
    for (int r = 0; r < 4; ++r) {
        sv0[r] = __shfl(inv0, kg * 4 + r);
        sv1[r] = __shfl(inv1, kg * 4 + r);
    }

    // ---- 16 channel-tiles: load x, cvt, 6 MFMA, store immediately ----
    const float* xbase = x + ((size_t)b * C_) * NT + LO + kg * 8;
    float* ob = out + ((size_t)b * C_) * TFEAT + t0 + kg * 4;

#pragma unroll 2
    for (int ct = 0; ct < 16; ++ct) {
        const float* xr = xbase + (size_t)(ct * 16 + fr) * NT;
        bf16x8 bfr[3];
#pragma unroll
        for (int ks = 0; ks < 3; ++ks) {
            f32x4 a0 = *reinterpret_cast<const f32x4*>(xr + ks * 32);
            f32x4 a1 = *reinterpret_cast<const f32x4*>(xr + ks * 32 + 4);
            bf16x8 vv;
#pragma unroll
            for (int q = 0; q < 4; ++q) {
                vv[q]     = (__bf16)a0[q];
                vv[q + 4] = (__bf16)a1[q];
            }
            bfr[ks] = vv;
        }
        f32x4 acc0 = (f32x4){0.f, 0.f, 0.f, 0.f};
        f32x4 acc1 = (f32x4){0.f, 0.f, 0.f, 0.f};
#pragma unroll
        for (int ks = 0; ks < 3; ++ks) {
            acc0 = __builtin_amdgcn_mfma_f32_16x16x32_bf16(af0[ks], bfr[ks], acc0, 0, 0, 0);
            acc1 = __builtin_amdgcn_mfma_f32_16x16x32_bf16(af1[ks], bfr[ks], acc1, 0, 0, 0);
        }
        // D: col = fr -> channel ct*16+fr, row = kg*4+r -> frame (+16 for acc1)
        float* op = ob + (size_t)(ct * 16 + fr) * TFEAT;
        __builtin_nontemporal_store(acc0 * sv0, reinterpret_cast<f32x4*>(op));
        __builtin_nontemporal_store(acc1 * sv1, reinterpret_cast<f32x4*>(op + 16));
    }
}

extern "C" void kernel_launch(void* const* d_in, const int* in_sizes, int n_in,
                              void* d_out, int out_size, void* d_ws, size_t ws_size,
                              hipStream_t stream) {
    const float* x = (const float*)d_in[0];
    const float* w = (const float*)d_in[1];
    // x_mask / y_mask are all-True in this problem: ignored.
    float* out  = (float*)d_out;
    float* cbuf = (float*)d_ws;                      // 64 KB centers
    int*   lotab = (int*)((char*)d_ws + 65536);      // 8 KB per-tile LO

    hipLaunchKernelGGL(prep_kernel, dim3(B_), dim3(256), 0, stream, w, cbuf, lotab);
    hipLaunchKernelGGL(g_kernel, dim3(B_ * (TFEAT / TT)), dim3(64), 0, stream,
                       x, cbuf, lotab, out);
}